// Round 13
// baseline (89.685 us; speedup 1.0000x reference)
//
#include <hip/hip_runtime.h>
#include <math.h>

#define B_ROWS 131072
#define NE 2048
#define ZDIM 64
#define THREADS 256

typedef __attribute__((ext_vector_type(8))) short short8;
typedef __attribute__((ext_vector_type(4))) float f32x4;

typedef const __attribute__((address_space(1))) void gv_t;
typedef __attribute__((address_space(3))) void lv_t;

// async global->LDS DMA, 16 B per lane. LDS dest = wave-uniform base + lane*16
// (m104); global src is per-lane (m173: pre-swizzled source pattern).
static __device__ __forceinline__ void gl_lds16(const void* g, void* l) {
    __builtin_amdgcn_global_load_lds((gv_t*)(uintptr_t)g,
                                     (lv_t*)(unsigned)(uintptr_t)l, 16, 0, 0);
}

// ---------------------------------------------------------------------------
// bf16 helpers (RNE), bit-exact with __float2bfloat16
// ---------------------------------------------------------------------------
static __device__ __forceinline__ unsigned short f2bf(float f) {
    unsigned int u = __float_as_uint(f);
    unsigned int r = (u + 0x7FFFu + ((u >> 16) & 1u)) >> 16;
    return (unsigned short)r;
}
static __device__ __forceinline__ float bf2f(unsigned short s) {
    return __uint_as_float(((unsigned int)s) << 16);
}

// ---------------------------------------------------------------------------
// Shared device helper: encoder (x -> z[64]), exact fp32.
// ---------------------------------------------------------------------------
__device__ __forceinline__ void encode_row(
    const float* __restrict__ xin,
    const float* __restrict__ W1, const float* __restrict__ b1,
    const float* __restrict__ W2, const float* __restrict__ b2,
    const float* __restrict__ W3, const float* __restrict__ b3,
    const float* __restrict__ W4, const float* __restrict__ b4,
    float* __restrict__ z) {
    float h1[16];
#pragma unroll
    for (int k = 0; k < 16; ++k) {
        float a = b1[k];
#pragma unroll
        for (int i = 0; i < 5; ++i) a = fmaf(xin[i], W1[i * 16 + k], a);
        h1[k] = fmaxf(a, 0.f);
    }
    float h2[32];
#pragma unroll
    for (int k = 0; k < 32; ++k) {
        float a = b2[k];
#pragma unroll
        for (int i = 0; i < 16; ++i) a = fmaf(h1[i], W2[i * 32 + k], a);
        h2[k] = fmaxf(a, 0.f);
    }
    float h3[16];
#pragma unroll
    for (int k = 0; k < 16; ++k) {
        float a = b3[k];
#pragma unroll
        for (int i = 0; i < 32; ++i) a = fmaf(h2[i], W3[i * 16 + k], a);
        h3[k] = fmaxf(a, 0.f);
    }
#pragma unroll
    for (int k = 0; k < ZDIM; ++k) {
        float a = b4[k];
#pragma unroll
        for (int i = 0; i < 16; ++i) a = fmaf(h3[i], W4[i * 64 + k], a);
        z[k] = a;
    }
}

// ---------------------------------------------------------------------------
// Kernel P: codebook prep only. Ebf = bf16(E), eNormHalf = 0.5*|bf16(e)|^2.
// ---------------------------------------------------------------------------
__global__ __launch_bounds__(THREADS) void prep_kernel(
    const float* __restrict__ E,
    unsigned short* __restrict__ Ebf,
    float* __restrict__ eNormHalf) {
    const int row = blockIdx.x * THREADS + threadIdx.x;
    if (row < NE) {
        float s = 0.f;
#pragma unroll
        for (int d = 0; d < ZDIM; ++d) {
            unsigned short bb = f2bf(E[row * ZDIM + d]);
            Ebf[row * ZDIM + d] = bb;
            float v = bf2f(bb);
            s = fmaf(v, v, s);
        }
        eNormHalf[row] = 0.5f * s;
    }
}

// ---------------------------------------------------------------------------
// Kernel S (scan, R13 codebook-split): grid (512 row-blocks, 2 halves).
// Block = 256 threads (4 waves x 64 rows), scans HALF the codebook (1024
// cols, 4 chunks of 256). Rationale: total waves were pinned at 2048 =
// 2/SIMD by rows-per-wave (the R6-R12 stall wall; VALU-issue is only ~14%
// per SIMD). Splitting the codebook doubles waves to 4096 with the SAME
// total instruction count (64 rows/wave kept — the R9-measured optimum).
// LDS = ebuf 32 KB + enorm 4 KB = 36 KB -> 4 blocks/CU -> 4 waves/SIMD.
// (256,4): VGPR cap 128 (scan core measured 88 in R8; WRITE = spill sentinel).
// Per-row candidates (score,idx) -> ws for the finish kernel's 2-way merge.
// DMA source-swizzle formula unchanged from R12 (q*32 ≡ 0 mod 8).
// ---------------------------------------------------------------------------
__global__ __launch_bounds__(THREADS, 4) void scan_kernel(
    const float* __restrict__ x,
    const float* __restrict__ W1, const float* __restrict__ b1,
    const float* __restrict__ W2, const float* __restrict__ b2,
    const float* __restrict__ W3, const float* __restrict__ b3,
    const float* __restrict__ W4, const float* __restrict__ b4,
    const unsigned short* __restrict__ Ebf,
    const float* __restrict__ eNormHalf,
    float* __restrict__ scoreBuf /* [2][B] */,
    int* __restrict__ idxBuf /* [2][B] */) {

    __shared__ unsigned short ebuf[256 * ZDIM];  // 32 KB; phase1: zbuf 32 KB
    __shared__ float enorm[1024];                // 4 KB (this half's norms)

    const int tid = threadIdx.x;
    const int lane = tid & 63;
    const int w = tid >> 6;  // 0..3
    const int l15 = lane & 15;
    const int lhi = lane >> 4;
    const int bx = blockIdx.x;
    const int s = blockIdx.y;  // codebook half

    // ---- stage this half's eNormHalf -> LDS (256 x float4 = 4 KB) ----
    {
        const float4* es = (const float4*)(eNormHalf + s * 1024);
        float4* ed = (float4*)enorm;
        ed[tid] = es[tid];
    }

    // ================= phase 1: encoder -> swizzled zbuf ===================
    const int myrow = bx * 256 + tid;
    float xin[5];
#pragma unroll
    for (int i = 0; i < 5; ++i) xin[i] = x[myrow * 5 + i];
    {
        float z[ZDIM];
        encode_row(xin, W1, b1, W2, b2, W3, b3, W4, b4, z);
        // R12-validated XOR swizzle: row t, slot q at t*128 + ((q^(t&7))<<4)
#pragma unroll
        for (int q = 0; q < 8; ++q) {
            short8 v;
#pragma unroll
            for (int e = 0; e < 8; ++e) v[e] = (short)f2bf(z[q * 8 + e]);
            *(short8*)((char*)ebuf + tid * 128 + ((q ^ (tid & 7)) << 4)) = v;
        }
    }
    __syncthreads();

    // ---- A fragments: 4 m-tiles x 2 k-halves from swizzled zbuf ----
    // row = w*64 + mt*16 + l15 -> row&7 = l15&7; slot = h*4 + lhi.
    short8 afr[4][2];
#pragma unroll
    for (int mt = 0; mt < 4; ++mt)
#pragma unroll
        for (int h = 0; h < 2; ++h) {
            const int row = w * 64 + mt * 16 + l15;
            const int slot = h * 4 + lhi;
            afr[mt][h] = *(const short8*)((const char*)ebuf + row * 128 +
                                          ((slot ^ (l15 & 7)) << 4));
        }
    __syncthreads();  // afr loads complete before DMA overwrites ebuf

    // ================= phase 2: scan this half (4 chunks x 256 cols) =======
    float best[4][4];
    int bidx[4][4];
#pragma unroll
    for (int mt = 0; mt < 4; ++mt)
#pragma unroll
        for (int r = 0; r < 4; ++r) {
            best[mt][r] = -INFINITY;
            bidx[mt][r] = s * 1024;
        }

    // per-lane pre-swizzled global byte offset (8 issues x 4 KB per chunk):
    // linear LDS slot L = q*4096 + tid*16 -> col = q*32 + (tid>>3), kb'=tid&7;
    // source slot = (col, kb' ^ (col&7)); col&7 == (tid>>3)&7 (q*32 = 0 mod 8).
    const int pi = (tid >> 3) * 128 + (((tid & 7) ^ ((tid >> 3) & 7)) << 4);
    const char* gb = (const char*)Ebf + s * 131072;  // half base (1024 cols)
    const int ldsw = w * 1024;  // wave-uniform DMA dest base (lane*16 HW-added)

    // per-lane LDS read bases (validated swizzle), hoisted
    const char* base0 =
        (const char*)&ebuf[0] + l15 * 128 + ((lhi ^ (l15 & 7)) << 4);
    const char* base1 =
        (const char*)&ebuf[0] + l15 * 128 + (((4 + lhi) ^ (l15 & 7)) << 4);
    const float* enb = enorm + l15;

    for (int c = 0; c < 4; ++c) {
        // ---- stage chunk c (8 DMA issues per thread, 32 KB) ----
#pragma unroll
        for (int q = 0; q < 8; ++q)
            gl_lds16(gb + c * 32768 + q * 4096 + pi,
                     (char*)&ebuf[0] + q * 4096 + ldsw);
        __syncthreads();  // full drain (vmcnt+lgkm) + barrier

        const float* enc = enb + c * 256;
        const int nb = s * 1024 + c * 256 + l15;

        // ---- 16 tiles, barrier-free (ds_read offsets fit immediates) ----
#pragma unroll 4
        for (int t = 0; t < 16; ++t) {
            short8 b0 = *(const short8*)(base0 + t * 2048);
            short8 b1 = *(const short8*)(base1 + t * 2048);
            const float negE = -enc[t * 16];
            f32x4 ci;
            ci[0] = negE; ci[1] = negE; ci[2] = negE; ci[3] = negE;

            f32x4 acc[4];
#pragma unroll
            for (int mt = 0; mt < 4; ++mt) {
                acc[mt] = __builtin_amdgcn_mfma_f32_16x16x32_bf16(afr[mt][0], b0, ci, 0, 0, 0);
                acc[mt] = __builtin_amdgcn_mfma_f32_16x16x32_bf16(afr[mt][1], b1, acc[mt], 0, 0, 0);
            }

            const int n = nb + t * 16;
#pragma unroll
            for (int mt = 0; mt < 4; ++mt) {
#pragma unroll
                for (int r = 0; r < 4; ++r) {
                    float sc = acc[mt][r];
                    if (sc > best[mt][r]) {  // strict '>' keeps first index
                        best[mt][r] = sc;
                        bidx[mt][r] = n;
                    }
                }
            }
        }
        __syncthreads();  // all waves done reading before next chunk's DMA
    }

    // ---- cross-lane reduction (16 lanes per row-group) -> candidates ----
#pragma unroll
    for (int mt = 0; mt < 4; ++mt)
#pragma unroll
        for (int r = 0; r < 4; ++r) {
            float sc = best[mt][r];
            int ix = bidx[mt][r];
#pragma unroll
            for (int off = 1; off < 16; off <<= 1) {
                float os = __shfl_xor(sc, off);
                int oi = __shfl_xor(ix, off);
                bool take = (os > sc) || (os == sc && oi < ix);
                sc = take ? os : sc;
                ix = take ? oi : ix;
            }
            if (l15 == 0) {
                const int row = bx * 256 + w * 64 + mt * 16 + lhi * 4 + r;
                scoreBuf[s * B_ROWS + row] = sc;
                idxBuf[s * B_ROWS + row] = ix;
            }
        }
}

// ---------------------------------------------------------------------------
// Kernel F: merge halves (tie -> half 0 = smaller index), recompute encoder,
// gather zq, decoder, losses, per-block partials.
// ---------------------------------------------------------------------------
__global__ __launch_bounds__(THREADS) void finish_rows_kernel(
    const float* __restrict__ x,
    const float* __restrict__ W1, const float* __restrict__ b1,
    const float* __restrict__ W2, const float* __restrict__ b2,
    const float* __restrict__ W3, const float* __restrict__ b3,
    const float* __restrict__ W4, const float* __restrict__ b4,
    const float* __restrict__ W5, const float* __restrict__ b5,
    const float* __restrict__ W6, const float* __restrict__ b6,
    const float* __restrict__ W7, const float* __restrict__ b7,
    const float* __restrict__ W8, const float* __restrict__ b8,
    const float* __restrict__ E,
    const float* __restrict__ scoreBuf, const int* __restrict__ idxBuf,
    float* __restrict__ partials) {

    const int row = blockIdx.x * THREADS + threadIdx.x;

    // ---- 2-way merge: strict '>' so ties pick half 0 (smaller index) ----
    const float sc0 = scoreBuf[row];
    const float sc1 = scoreBuf[B_ROWS + row];
    const int ix0 = idxBuf[row];
    const int ix1 = idxBuf[B_ROWS + row];
    const int bidx = (sc1 > sc0) ? ix1 : ix0;

    float xin[5];
#pragma unroll
    for (int i = 0; i < 5; ++i) xin[i] = x[row * 5 + i];
    float z[ZDIM];
    encode_row(xin, W1, b1, W2, b2, W3, b3, W4, b4, z);

    float zq[ZDIM];
#pragma unroll
    for (int d = 0; d < ZDIM; ++d) zq[d] = E[bidx * ZDIM + d];

    float emb = 0.f;
#pragma unroll
    for (int d = 0; d < ZDIM; ++d) {
        float diff = z[d] - zq[d];
        emb = fmaf(diff, diff, emb);
    }
    emb *= 2.0f;  // embed + BETA*commit, BETA=1

    float g1[16];
#pragma unroll
    for (int k = 0; k < 16; ++k) {
        float a = b5[k];
#pragma unroll
        for (int i = 0; i < ZDIM; ++i) a = fmaf(zq[i], W5[i * 16 + k], a);
        g1[k] = fmaxf(a, 0.f);
    }
    float g2[32];
#pragma unroll
    for (int k = 0; k < 32; ++k) {
        float a = b6[k];
#pragma unroll
        for (int i = 0; i < 16; ++i) a = fmaf(g1[i], W6[i * 32 + k], a);
        g2[k] = fmaxf(a, 0.f);
    }
    float g3[16];
#pragma unroll
    for (int k = 0; k < 16; ++k) {
        float a = b7[k];
#pragma unroll
        for (int i = 0; i < 32; ++i) a = fmaf(g2[i], W7[i * 16 + k], a);
        g3[k] = fmaxf(a, 0.f);
    }
    float l2 = 0.f;
#pragma unroll
    for (int k = 0; k < 5; ++k) {
        float a = b8[k];
#pragma unroll
        for (int i = 0; i < 16; ++i) a = fmaf(g3[i], W8[i * 5 + k], a);
        float diff = xin[k] - a;
        l2 = fmaf(diff, diff, l2);
    }

#pragma unroll
    for (int off = 32; off > 0; off >>= 1) {
        l2 += __shfl_down(l2, off);
        emb += __shfl_down(emb, off);
    }
    __shared__ float sl[THREADS / 64], se[THREADS / 64];
    const int wid = threadIdx.x >> 6;
    if ((threadIdx.x & 63) == 0) {
        sl[wid] = l2;
        se[wid] = emb;
    }
    __syncthreads();
    if (threadIdx.x == 0) {
        float L = 0.f, Em = 0.f;
#pragma unroll
        for (int ww = 0; ww < THREADS / 64; ++ww) {
            L += sl[ww];
            Em += se[ww];
        }
        partials[2 * blockIdx.x + 0] = L;
        partials[2 * blockIdx.x + 1] = Em;
    }
}

// ---------------------------------------------------------------------------
// Fallback path kernels (ws too small) — proven R1 monolithic fp32.
// ---------------------------------------------------------------------------
__global__ void enorm_kernel(const float* __restrict__ E,
                             float* __restrict__ eNormHalf) {
    int j = blockIdx.x * blockDim.x + threadIdx.x;
    if (j < NE) {
        float s = 0.f;
#pragma unroll
        for (int d = 0; d < ZDIM; ++d) {
            float v = E[j * ZDIM + d];
            s = fmaf(v, v, s);
        }
        eNormHalf[j] = 0.5f * s;
    }
}

__global__ __launch_bounds__(THREADS) void vqvae_main_kernel(
    const float* __restrict__ x,
    const float* __restrict__ W1, const float* __restrict__ b1,
    const float* __restrict__ W2, const float* __restrict__ b2,
    const float* __restrict__ W3, const float* __restrict__ b3,
    const float* __restrict__ W4, const float* __restrict__ b4,
    const float* __restrict__ W5, const float* __restrict__ b5,
    const float* __restrict__ W6, const float* __restrict__ b6,
    const float* __restrict__ W7, const float* __restrict__ b7,
    const float* __restrict__ W8, const float* __restrict__ b8,
    const float* __restrict__ E, const float* __restrict__ eNormHalf,
    float* __restrict__ partials) {

    const int row = blockIdx.x * blockDim.x + threadIdx.x;
    float l2 = 0.f, emb = 0.f;

    if (row < B_ROWS) {
        float xin[5];
#pragma unroll
        for (int i = 0; i < 5; ++i) xin[i] = x[row * 5 + i];
        float z[ZDIM];
        encode_row(xin, W1, b1, W2, b2, W3, b3, W4, b4, z);

        float best = -INFINITY;
        int bidx = 0;
        const float4* __restrict__ E4 = reinterpret_cast<const float4*>(E);
        for (int j = 0; j < NE; ++j) {
            float a0 = 0.f, a1 = 0.f, a2 = 0.f, a3 = 0.f;
#pragma unroll
            for (int q = 0; q < ZDIM / 4; ++q) {
                float4 e = E4[j * (ZDIM / 4) + q];
                a0 = fmaf(z[4 * q + 0], e.x, a0);
                a1 = fmaf(z[4 * q + 1], e.y, a1);
                a2 = fmaf(z[4 * q + 2], e.z, a2);
                a3 = fmaf(z[4 * q + 3], e.w, a3);
            }
            float score = ((a0 + a1) + (a2 + a3)) - eNormHalf[j];
            if (score > best) { best = score; bidx = j; }
        }
        float zq[ZDIM];
#pragma unroll
        for (int d = 0; d < ZDIM; ++d) zq[d] = E[bidx * ZDIM + d];
#pragma unroll
        for (int d = 0; d < ZDIM; ++d) {
            float diff = z[d] - zq[d];
            emb = fmaf(diff, diff, emb);
        }
        emb *= 2.0f;
        float g1[16];
#pragma unroll
        for (int k = 0; k < 16; ++k) {
            float a = b5[k];
#pragma unroll
            for (int i = 0; i < ZDIM; ++i) a = fmaf(zq[i], W5[i * 16 + k], a);
            g1[k] = fmaxf(a, 0.f);
        }
        float g2[32];
#pragma unroll
        for (int k = 0; k < 32; ++k) {
            float a = b6[k];
#pragma unroll
            for (int i = 0; i < 16; ++i) a = fmaf(g1[i], W6[i * 32 + k], a);
            g2[k] = fmaxf(a, 0.f);
        }
        float g3[16];
#pragma unroll
        for (int k = 0; k < 16; ++k) {
            float a = b7[k];
#pragma unroll
            for (int i = 0; i < 32; ++i) a = fmaf(g2[i], W7[i * 16 + k], a);
            g3[k] = fmaxf(a, 0.f);
        }
#pragma unroll
        for (int k = 0; k < 5; ++k) {
            float a = b8[k];
#pragma unroll
            for (int i = 0; i < 16; ++i) a = fmaf(g3[i], W8[i * 5 + k], a);
            float diff = xin[k] - a;
            l2 = fmaf(diff, diff, l2);
        }
    }
#pragma unroll
    for (int off = 32; off > 0; off >>= 1) {
        l2 += __shfl_down(l2, off);
        emb += __shfl_down(emb, off);
    }
    __shared__ float sl[THREADS / 64], se[THREADS / 64];
    const int wid = threadIdx.x >> 6;
    if ((threadIdx.x & 63) == 0) { sl[wid] = l2; se[wid] = emb; }
    __syncthreads();
    if (threadIdx.x == 0) {
        float L = 0.f, Em = 0.f;
#pragma unroll
        for (int ww = 0; ww < THREADS / 64; ++ww) { L += sl[ww]; Em += se[ww]; }
        partials[2 * blockIdx.x + 0] = L;
        partials[2 * blockIdx.x + 1] = Em;
    }
}

// ---------------------------------------------------------------------------
// Final reduce: per-block partials (double accumulation) -> 3 scalars.
// ---------------------------------------------------------------------------
__global__ void finalize_kernel(const float* __restrict__ partials, int nblocks,
                                float* __restrict__ out) {
    __shared__ double sl[256], se[256];
    double a = 0.0, b = 0.0;
    for (int i = threadIdx.x; i < nblocks; i += 256) {
        a += (double)partials[2 * i + 0];
        b += (double)partials[2 * i + 1];
    }
    sl[threadIdx.x] = a;
    se[threadIdx.x] = b;
    __syncthreads();
    for (int s = 128; s > 0; s >>= 1) {
        if (threadIdx.x < s) {
            sl[threadIdx.x] += sl[threadIdx.x + s];
            se[threadIdx.x] += se[threadIdx.x + s];
        }
        __syncthreads();
    }
    if (threadIdx.x == 0) {
        double sum_l2 = sl[0];
        double embd = se[0];
        double c = -0.5 * 5.0 * log(2.0 * M_PI / 10.0);
        double neg_pxz = -(c - 5.0 * sum_l2);
        out[0] = (float)(neg_pxz + embd);
        out[1] = (float)neg_pxz;
        out[2] = (float)embd;
    }
}

// ---------------------------------------------------------------------------
extern "C" void kernel_launch(void* const* d_in, const int* in_sizes, int n_in,
                              void* d_out, int out_size, void* d_ws,
                              size_t ws_size, hipStream_t stream) {
    const float* x = (const float*)d_in[0];
    const float* W1 = (const float*)d_in[1];
    const float* b1 = (const float*)d_in[2];
    const float* W2 = (const float*)d_in[3];
    const float* b2 = (const float*)d_in[4];
    const float* W3 = (const float*)d_in[5];
    const float* b3 = (const float*)d_in[6];
    const float* W4 = (const float*)d_in[7];
    const float* b4 = (const float*)d_in[8];
    const float* W5 = (const float*)d_in[9];
    const float* b5 = (const float*)d_in[10];
    const float* W6 = (const float*)d_in[11];
    const float* b6 = (const float*)d_in[12];
    const float* W7 = (const float*)d_in[13];
    const float* b7 = (const float*)d_in[14];
    const float* W8 = (const float*)d_in[15];
    const float* b8 = (const float*)d_in[16];
    const float* E = (const float*)d_in[17];

    // ws layout (16B-aligned segments)
    char* ws = (char*)d_ws;
    unsigned short* Ebf      = (unsigned short*)(ws + 0);        // 256 KB
    float*          eNormH   = (float*)(ws + 262144);            // 8 KB
    float*          scoreBuf = (float*)(ws + 270336);            // 1 MB
    int*            idxBuf   = (int*)(ws + 270336 + 1048576);    // 1 MB
    float*          partials = (float*)(ws + 270336 + 2097152);  // 4 KB
    const size_t need = 270336 + 2097152 + 512 * 2 * sizeof(float);

    if (ws_size >= need) {
        const int nblocks = B_ROWS / 256;  // 512
        prep_kernel<<<NE / THREADS, THREADS, 0, stream>>>(E, Ebf, eNormH);
        dim3 sgrid(nblocks, 2);
        scan_kernel<<<sgrid, THREADS, 0, stream>>>(
            x, W1, b1, W2, b2, W3, b3, W4, b4, Ebf, eNormH, scoreBuf, idxBuf);
        finish_rows_kernel<<<nblocks, THREADS, 0, stream>>>(
            x, W1, b1, W2, b2, W3, b3, W4, b4, W5, b5, W6, b6, W7, b7, W8, b8,
            E, scoreBuf, idxBuf, partials);
        finalize_kernel<<<1, 256, 0, stream>>>(partials, nblocks, (float*)d_out);
    } else {
        // fallback: proven fp32 monolithic path
        const int nblocks = B_ROWS / THREADS;  // 512
        float* eNormFB = (float*)ws;           // 8 KB
        float* partFB  = (float*)(ws + 16384);
        enorm_kernel<<<(NE + THREADS - 1) / THREADS, THREADS, 0, stream>>>(E, eNormFB);
        vqvae_main_kernel<<<nblocks, THREADS, 0, stream>>>(
            x, W1, b1, W2, b2, W3, b3, W4, b4, W5, b5, W6, b6, W7, b7, W8, b8,
            E, eNormFB, partFB);
        finalize_kernel<<<1, 256, 0, stream>>>(partFB, nblocks, (float*)d_out);
    }
}

// Round 14
// 76.228 us; speedup vs baseline: 1.1765x; 1.1765x over previous
//
#include <hip/hip_runtime.h>
#include <math.h>

#define B_ROWS 131072
#define NE 2048
#define ZDIM 64
#define THREADS 256

typedef __attribute__((ext_vector_type(8))) short short8;
typedef __attribute__((ext_vector_type(4))) float f32x4;

typedef const __attribute__((address_space(1))) void gv_t;
typedef __attribute__((address_space(3))) void lv_t;

// async global->LDS DMA, 16 B per lane. LDS dest = wave-uniform base + lane*16
// (m104); global src is per-lane (m173: pre-swizzled source pattern).
static __device__ __forceinline__ void gl_lds16(const void* g, void* l) {
    __builtin_amdgcn_global_load_lds((gv_t*)(uintptr_t)g,
                                     (lv_t*)(unsigned)(uintptr_t)l, 16, 0, 0);
}

// ---------------------------------------------------------------------------
// bf16 helpers (RNE), bit-exact with __float2bfloat16
// ---------------------------------------------------------------------------
static __device__ __forceinline__ unsigned short f2bf(float f) {
    unsigned int u = __float_as_uint(f);
    unsigned int r = (u + 0x7FFFu + ((u >> 16) & 1u)) >> 16;
    return (unsigned short)r;
}
static __device__ __forceinline__ float bf2f(unsigned short s) {
    return __uint_as_float(((unsigned int)s) << 16);
}

// ---------------------------------------------------------------------------
// Shared device helper: encoder (x -> z[64]), exact fp32.
// ---------------------------------------------------------------------------
__device__ __forceinline__ void encode_row(
    const float* __restrict__ xin,
    const float* __restrict__ W1, const float* __restrict__ b1,
    const float* __restrict__ W2, const float* __restrict__ b2,
    const float* __restrict__ W3, const float* __restrict__ b3,
    const float* __restrict__ W4, const float* __restrict__ b4,
    float* __restrict__ z) {
    float h1[16];
#pragma unroll
    for (int k = 0; k < 16; ++k) {
        float a = b1[k];
#pragma unroll
        for (int i = 0; i < 5; ++i) a = fmaf(xin[i], W1[i * 16 + k], a);
        h1[k] = fmaxf(a, 0.f);
    }
    float h2[32];
#pragma unroll
    for (int k = 0; k < 32; ++k) {
        float a = b2[k];
#pragma unroll
        for (int i = 0; i < 16; ++i) a = fmaf(h1[i], W2[i * 32 + k], a);
        h2[k] = fmaxf(a, 0.f);
    }
    float h3[16];
#pragma unroll
    for (int k = 0; k < 16; ++k) {
        float a = b3[k];
#pragma unroll
        for (int i = 0; i < 32; ++i) a = fmaf(h2[i], W3[i * 16 + k], a);
        h3[k] = fmaxf(a, 0.f);
    }
#pragma unroll
    for (int k = 0; k < ZDIM; ++k) {
        float a = b4[k];
#pragma unroll
        for (int i = 0; i < 16; ++i) a = fmaf(h3[i], W4[i * 64 + k], a);
        z[k] = a;
    }
}

// ---------------------------------------------------------------------------
// Kernel P: codebook prep only. Ebf = bf16(E), eNormHalf = 0.5*|bf16(e)|^2.
// ---------------------------------------------------------------------------
__global__ __launch_bounds__(THREADS) void prep_kernel(
    const float* __restrict__ E,
    unsigned short* __restrict__ Ebf,
    float* __restrict__ eNormHalf) {
    const int row = blockIdx.x * THREADS + threadIdx.x;
    if (row < NE) {
        float s = 0.f;
#pragma unroll
        for (int d = 0; d < ZDIM; ++d) {
            unsigned short bb = f2bf(E[row * ZDIM + d]);
            Ebf[row * ZDIM + d] = bb;
            float v = bf2f(bb);
            s = fmaf(v, v, s);
        }
        eNormHalf[row] = 0.5f * s;
    }
}

// ---------------------------------------------------------------------------
// Kernel M (mega, R14 = R12 base + wave-uniform argmax skip):
// R6-R13 established the scan is issue-bound, and the per-tile budget shows
// argmax bookkeeping (3 VALU x 16 slots) is ~55% of busy cycles — bigger
// than the MFMAs. Each slot expects only ~ln(128)≈5 updates over the whole
// scan, so the update body is almost always a wave-wide no-op:
//   4 v_cmp per mt + __any -> s_cbranch skips the 8-cndmask body (~14% taken)
// Everything else (R12 structure: 4 waves x 64 rows, z in VGPRs, swizzled
// zbuf, DMA source-swizzle, 4 chunks x 512 cols) is byte-identical to R12.
// ---------------------------------------------------------------------------
__global__ __launch_bounds__(THREADS, 2) void mega_kernel(
    const float* __restrict__ x,
    const float* __restrict__ W1, const float* __restrict__ b1,
    const float* __restrict__ W2, const float* __restrict__ b2,
    const float* __restrict__ W3, const float* __restrict__ b3,
    const float* __restrict__ W4, const float* __restrict__ b4,
    const float* __restrict__ W5, const float* __restrict__ b5,
    const float* __restrict__ W6, const float* __restrict__ b6,
    const float* __restrict__ W7, const float* __restrict__ b7,
    const float* __restrict__ W8, const float* __restrict__ b8,
    const float* __restrict__ E,
    const unsigned short* __restrict__ Ebf,
    const float* __restrict__ eNormHalf,
    float* __restrict__ partials) {

    __shared__ unsigned short ebuf[512 * ZDIM];  // 64 KB; first 32 KB = zbuf
    __shared__ float enorm[NE];                  // 8 KB
    __shared__ float sl[THREADS / 64], se[THREADS / 64];

    const int tid = threadIdx.x;
    const int lane = tid & 63;
    const int w = tid >> 6;  // 0..3
    const int l15 = lane & 15;
    const int lhi = lane >> 4;

    // ---- stage full eNormHalf -> LDS (8 KB) ----
    {
        const float4* es = (const float4*)eNormHalf;
        float4* ed = (float4*)enorm;
        ed[tid] = es[tid];
        ed[tid + 256] = es[tid + 256];
    }

    // ================= phase 1: encoder (z stays in VGPRs) =================
    const int myrow = blockIdx.x * 256 + tid;
    float xin[5];
#pragma unroll
    for (int i = 0; i < 5; ++i) xin[i] = x[myrow * 5 + i];
    float z[ZDIM];
    encode_row(xin, W1, b1, W2, b2, W3, b3, W4, b4, z);

    // bf16 z -> LDS zbuf, XOR-swizzled 16B slots (R12-validated, 0 conflicts)
#pragma unroll
    for (int q = 0; q < 8; ++q) {
        short8 v;
#pragma unroll
        for (int e = 0; e < 8; ++e) v[e] = (short)f2bf(z[q * 8 + e]);
        *(short8*)((char*)ebuf + tid * 128 + ((q ^ (tid & 7)) << 4)) = v;
    }
    __syncthreads();

    // ---- A fragments: 4 m-tiles x 2 k-halves from swizzled zbuf ----
    // row = w*64 + mt*16 + l15 -> row&7 = l15&7; slot = h*4 + lhi.
    short8 afr[4][2];
#pragma unroll
    for (int mt = 0; mt < 4; ++mt)
#pragma unroll
        for (int h = 0; h < 2; ++h) {
            const int row = w * 64 + mt * 16 + l15;
            const int slot = h * 4 + lhi;
            afr[mt][h] = *(const short8*)((const char*)ebuf + row * 128 +
                                          ((slot ^ (l15 & 7)) << 4));
        }
    __syncthreads();  // afr loads complete before DMA overwrites ebuf

    // ================= phase 2: scan =======================================
    float best[4][4];
    int bidx[4][4];
#pragma unroll
    for (int mt = 0; mt < 4; ++mt)
#pragma unroll
        for (int r = 0; r < 4; ++r) {
            best[mt][r] = -INFINITY;
            bidx[mt][r] = 0;
        }

    // per-lane pre-swizzled global byte offset (16 issues x 4 KB per chunk):
    // linear LDS slot L = q*4096 + tid*16 -> col = q*32 + (tid>>3), kb' = tid&7;
    // source slot = (col, kb' ^ (col&7)); col&7 == (tid>>3)&7 (q*32 = 0 mod 8).
    const int pi = (tid >> 3) * 128 + (((tid & 7) ^ ((tid >> 3) & 7)) << 4);
    const char* gb = (const char*)Ebf;
    const int ldsw = w * 1024;  // wave-uniform DMA dest base (lane*16 HW-added)

    // per-lane LDS read bases (validated swizzle), hoisted
    const char* base0 =
        (const char*)&ebuf[0] + l15 * 128 + ((lhi ^ (l15 & 7)) << 4);
    const char* base1 =
        (const char*)&ebuf[0] + l15 * 128 + (((4 + lhi) ^ (l15 & 7)) << 4);
    const float* enb = enorm + l15;

    for (int c = 0; c < 4; ++c) {
        // ---- stage chunk c (16 DMA issues per thread) ----
#pragma unroll
        for (int q = 0; q < 16; ++q)
            gl_lds16(gb + c * 65536 + q * 4096 + pi,
                     (char*)&ebuf[0] + q * 4096 + ldsw);
        __syncthreads();  // full drain (vmcnt+lgkm) + barrier

        const float* enc = enb + c * 512;
        const int nb = c * 512 + l15;

        // ---- 32 tiles, barrier-free (all ds_read offsets fit immediates) ----
#pragma unroll 4
        for (int t = 0; t < 32; ++t) {
            short8 b0 = *(const short8*)(base0 + t * 2048);
            short8 b1 = *(const short8*)(base1 + t * 2048);
            const float negE = -enc[t * 16];
            f32x4 ci;
            ci[0] = negE; ci[1] = negE; ci[2] = negE; ci[3] = negE;

            f32x4 acc[4];
#pragma unroll
            for (int mt = 0; mt < 4; ++mt) {
                acc[mt] = __builtin_amdgcn_mfma_f32_16x16x32_bf16(afr[mt][0], b0, ci, 0, 0, 0);
                acc[mt] = __builtin_amdgcn_mfma_f32_16x16x32_bf16(afr[mt][1], b1, acc[mt], 0, 0, 0);
            }

            const int n = nb + t * 16;
            // ---- argmax with wave-uniform skip: update body is a no-op for
            // the whole wave ~86% of the time (each slot updates ~ln(128)
            // times over 128 tiles) -> s_cbranch skips the cndmask block.
#pragma unroll
            for (int mt = 0; mt < 4; ++mt) {
                const bool u0 = acc[mt][0] > best[mt][0];
                const bool u1 = acc[mt][1] > best[mt][1];
                const bool u2 = acc[mt][2] > best[mt][2];
                const bool u3 = acc[mt][3] > best[mt][3];
                if (__any(u0 | u1 | u2 | u3)) {
#pragma unroll
                    for (int r = 0; r < 4; ++r) {
                        if (acc[mt][r] > best[mt][r]) {  // strict '>': first idx
                            best[mt][r] = acc[mt][r];
                            bidx[mt][r] = n;
                        }
                    }
                }
            }
        }
        __syncthreads();  // all waves done reading before next chunk's DMA
    }

    // ---- cross-lane reduction (16 lanes per row-group) -> idx into LDS ----
    int* idxbuf = (int*)ebuf;  // ebuf free after last chunk barrier
#pragma unroll
    for (int mt = 0; mt < 4; ++mt)
#pragma unroll
        for (int r = 0; r < 4; ++r) {
            float s = best[mt][r];
            int ix = bidx[mt][r];
#pragma unroll
            for (int off = 1; off < 16; off <<= 1) {
                float os = __shfl_xor(s, off);
                int oi = __shfl_xor(ix, off);
                bool take = (os > s) || (os == s && oi < ix);
                s = take ? os : s;
                ix = take ? oi : ix;
            }
            if (l15 == 0)
                idxbuf[w * 64 + mt * 16 + lhi * 4 + r] = ix;
        }
    __syncthreads();

    // ================= phase 3: gather + decoder + losses ==================
    const int myidx = idxbuf[tid];

    float zq[ZDIM];
#pragma unroll
    for (int d = 0; d < ZDIM; ++d) zq[d] = E[myidx * ZDIM + d];

    float emb = 0.f;
#pragma unroll
    for (int d = 0; d < ZDIM; ++d) {
        float diff = z[d] - zq[d];
        emb = fmaf(diff, diff, emb);
    }
    emb *= 2.0f;  // embed + BETA*commit, BETA=1

    float g1[16];
#pragma unroll
    for (int k = 0; k < 16; ++k) {
        float a = b5[k];
#pragma unroll
        for (int i = 0; i < ZDIM; ++i) a = fmaf(zq[i], W5[i * 16 + k], a);
        g1[k] = fmaxf(a, 0.f);
    }
    float g2[32];
#pragma unroll
    for (int k = 0; k < 32; ++k) {
        float a = b6[k];
#pragma unroll
        for (int i = 0; i < 16; ++i) a = fmaf(g1[i], W6[i * 32 + k], a);
        g2[k] = fmaxf(a, 0.f);
    }
    float g3[16];
#pragma unroll
    for (int k = 0; k < 16; ++k) {
        float a = b7[k];
#pragma unroll
        for (int i = 0; i < 32; ++i) a = fmaf(g2[i], W7[i * 16 + k], a);
        g3[k] = fmaxf(a, 0.f);
    }
    float l2 = 0.f;
#pragma unroll
    for (int k = 0; k < 5; ++k) {
        float a = b8[k];
#pragma unroll
        for (int i = 0; i < 16; ++i) a = fmaf(g3[i], W8[i * 5 + k], a);
        float diff = xin[k] - a;
        l2 = fmaf(diff, diff, l2);
    }

#pragma unroll
    for (int off = 32; off > 0; off >>= 1) {
        l2 += __shfl_down(l2, off);
        emb += __shfl_down(emb, off);
    }
    if ((tid & 63) == 0) {
        sl[w] = l2;
        se[w] = emb;
    }
    __syncthreads();
    if (tid == 0) {
        float L = 0.f, Em = 0.f;
#pragma unroll
        for (int ww = 0; ww < THREADS / 64; ++ww) {
            L += sl[ww];
            Em += se[ww];
        }
        partials[2 * blockIdx.x + 0] = L;
        partials[2 * blockIdx.x + 1] = Em;
    }
}

// ---------------------------------------------------------------------------
// Fallback path kernels (ws too small) — proven R1 monolithic fp32.
// ---------------------------------------------------------------------------
__global__ void enorm_kernel(const float* __restrict__ E,
                             float* __restrict__ eNormHalf) {
    int j = blockIdx.x * blockDim.x + threadIdx.x;
    if (j < NE) {
        float s = 0.f;
#pragma unroll
        for (int d = 0; d < ZDIM; ++d) {
            float v = E[j * ZDIM + d];
            s = fmaf(v, v, s);
        }
        eNormHalf[j] = 0.5f * s;
    }
}

__global__ __launch_bounds__(THREADS) void vqvae_main_kernel(
    const float* __restrict__ x,
    const float* __restrict__ W1, const float* __restrict__ b1,
    const float* __restrict__ W2, const float* __restrict__ b2,
    const float* __restrict__ W3, const float* __restrict__ b3,
    const float* __restrict__ W4, const float* __restrict__ b4,
    const float* __restrict__ W5, const float* __restrict__ b5,
    const float* __restrict__ W6, const float* __restrict__ b6,
    const float* __restrict__ W7, const float* __restrict__ b7,
    const float* __restrict__ W8, const float* __restrict__ b8,
    const float* __restrict__ E, const float* __restrict__ eNormHalf,
    float* __restrict__ partials) {

    const int row = blockIdx.x * blockDim.x + threadIdx.x;
    float l2 = 0.f, emb = 0.f;

    if (row < B_ROWS) {
        float xin[5];
#pragma unroll
        for (int i = 0; i < 5; ++i) xin[i] = x[row * 5 + i];
        float z[ZDIM];
        encode_row(xin, W1, b1, W2, b2, W3, b3, W4, b4, z);

        float best = -INFINITY;
        int bidx = 0;
        const float4* __restrict__ E4 = reinterpret_cast<const float4*>(E);
        for (int j = 0; j < NE; ++j) {
            float a0 = 0.f, a1 = 0.f, a2 = 0.f, a3 = 0.f;
#pragma unroll
            for (int q = 0; q < ZDIM / 4; ++q) {
                float4 e = E4[j * (ZDIM / 4) + q];
                a0 = fmaf(z[4 * q + 0], e.x, a0);
                a1 = fmaf(z[4 * q + 1], e.y, a1);
                a2 = fmaf(z[4 * q + 2], e.z, a2);
                a3 = fmaf(z[4 * q + 3], e.w, a3);
            }
            float score = ((a0 + a1) + (a2 + a3)) - eNormHalf[j];
            if (score > best) { best = score; bidx = j; }
        }
        float zq[ZDIM];
#pragma unroll
        for (int d = 0; d < ZDIM; ++d) zq[d] = E[bidx * ZDIM + d];
#pragma unroll
        for (int d = 0; d < ZDIM; ++d) {
            float diff = z[d] - zq[d];
            emb = fmaf(diff, diff, emb);
        }
        emb *= 2.0f;
        float g1[16];
#pragma unroll
        for (int k = 0; k < 16; ++k) {
            float a = b5[k];
#pragma unroll
            for (int i = 0; i < ZDIM; ++i) a = fmaf(zq[i], W5[i * 16 + k], a);
            g1[k] = fmaxf(a, 0.f);
        }
        float g2[32];
#pragma unroll
        for (int k = 0; k < 32; ++k) {
            float a = b6[k];
#pragma unroll
            for (int i = 0; i < 16; ++i) a = fmaf(g1[i], W6[i * 32 + k], a);
            g2[k] = fmaxf(a, 0.f);
        }
        float g3[16];
#pragma unroll
        for (int k = 0; k < 16; ++k) {
            float a = b7[k];
#pragma unroll
            for (int i = 0; i < 32; ++i) a = fmaf(g2[i], W7[i * 16 + k], a);
            g3[k] = fmaxf(a, 0.f);
        }
#pragma unroll
        for (int k = 0; k < 5; ++k) {
            float a = b8[k];
#pragma unroll
            for (int i = 0; i < 16; ++i) a = fmaf(g3[i], W8[i * 5 + k], a);
            float diff = xin[k] - a;
            l2 = fmaf(diff, diff, l2);
        }
    }
#pragma unroll
    for (int off = 32; off > 0; off >>= 1) {
        l2 += __shfl_down(l2, off);
        emb += __shfl_down(emb, off);
    }
    __shared__ float sl[THREADS / 64], se[THREADS / 64];
    const int wid = threadIdx.x >> 6;
    if ((threadIdx.x & 63) == 0) { sl[wid] = l2; se[wid] = emb; }
    __syncthreads();
    if (threadIdx.x == 0) {
        float L = 0.f, Em = 0.f;
#pragma unroll
        for (int ww = 0; ww < THREADS / 64; ++ww) { L += sl[ww]; Em += se[ww]; }
        partials[2 * blockIdx.x + 0] = L;
        partials[2 * blockIdx.x + 1] = Em;
    }
}

// ---------------------------------------------------------------------------
// Final reduce: per-block partials (double accumulation) -> 3 scalars.
// ---------------------------------------------------------------------------
__global__ void finalize_kernel(const float* __restrict__ partials, int nblocks,
                                float* __restrict__ out) {
    __shared__ double sl[256], se[256];
    double a = 0.0, b = 0.0;
    for (int i = threadIdx.x; i < nblocks; i += 256) {
        a += (double)partials[2 * i + 0];
        b += (double)partials[2 * i + 1];
    }
    sl[threadIdx.x] = a;
    se[threadIdx.x] = b;
    __syncthreads();
    for (int s = 128; s > 0; s >>= 1) {
        if (threadIdx.x < s) {
            sl[threadIdx.x] += sl[threadIdx.x + s];
            se[threadIdx.x] += se[threadIdx.x + s];
        }
        __syncthreads();
    }
    if (threadIdx.x == 0) {
        double sum_l2 = sl[0];
        double embd = se[0];
        double c = -0.5 * 5.0 * log(2.0 * M_PI / 10.0);
        double neg_pxz = -(c - 5.0 * sum_l2);
        out[0] = (float)(neg_pxz + embd);
        out[1] = (float)neg_pxz;
        out[2] = (float)embd;
    }
}

// ---------------------------------------------------------------------------
extern "C" void kernel_launch(void* const* d_in, const int* in_sizes, int n_in,
                              void* d_out, int out_size, void* d_ws,
                              size_t ws_size, hipStream_t stream) {
    const float* x = (const float*)d_in[0];
    const float* W1 = (const float*)d_in[1];
    const float* b1 = (const float*)d_in[2];
    const float* W2 = (const float*)d_in[3];
    const float* b2 = (const float*)d_in[4];
    const float* W3 = (const float*)d_in[5];
    const float* b3 = (const float*)d_in[6];
    const float* W4 = (const float*)d_in[7];
    const float* b4 = (const float*)d_in[8];
    const float* W5 = (const float*)d_in[9];
    const float* b5 = (const float*)d_in[10];
    const float* W6 = (const float*)d_in[11];
    const float* b6 = (const float*)d_in[12];
    const float* W7 = (const float*)d_in[13];
    const float* b7 = (const float*)d_in[14];
    const float* W8 = (const float*)d_in[15];
    const float* b8 = (const float*)d_in[16];
    const float* E = (const float*)d_in[17];

    // ws layout (16B-aligned segments)
    char* ws = (char*)d_ws;
    unsigned short* Ebf      = (unsigned short*)(ws + 0);       // 256 KB
    float*          eNormH   = (float*)(ws + 262144);           // 8 KB
    float*          partials = (float*)(ws + 270336);           // 4 KB
    const size_t need = 270336 + 512 * 2 * sizeof(float);

    if (ws_size >= need) {
        const int mblocks = B_ROWS / 256;  // 512
        prep_kernel<<<NE / THREADS, THREADS, 0, stream>>>(E, Ebf, eNormH);
        mega_kernel<<<mblocks, THREADS, 0, stream>>>(
            x, W1, b1, W2, b2, W3, b3, W4, b4, W5, b5, W6, b6, W7, b7, W8, b8,
            E, Ebf, eNormH, partials);
        finalize_kernel<<<1, 256, 0, stream>>>(partials, mblocks, (float*)d_out);
    } else {
        // fallback: proven fp32 monolithic path
        const int nblocks = B_ROWS / THREADS;  // 512
        float* eNormFB = (float*)ws;           // 8 KB
        float* partFB  = (float*)(ws + 16384);
        enorm_kernel<<<(NE + THREADS - 1) / THREADS, THREADS, 0, stream>>>(E, eNormFB);
        vqvae_main_kernel<<<nblocks, THREADS, 0, stream>>>(
            x, W1, b1, W2, b2, W3, b3, W4, b4, W5, b5, W6, b6, W7, b7, W8, b8,
            E, eNormFB, partFB);
        finalize_kernel<<<1, 256, 0, stream>>>(partFB, nblocks, (float*)d_out);
    }
}

// Round 15
// 72.845 us; speedup vs baseline: 1.2312x; 1.0464x over previous
//
#include <hip/hip_runtime.h>
#include <math.h>

#define B_ROWS 131072
#define NE 2048
#define ZDIM 64
#define THREADS 256

typedef __attribute__((ext_vector_type(8))) short short8;
typedef __attribute__((ext_vector_type(4))) float f32x4;

typedef const __attribute__((address_space(1))) void gv_t;
typedef __attribute__((address_space(3))) void lv_t;

// async global->LDS DMA, 16 B per lane. LDS dest = wave-uniform base + lane*16
// (m104); global src is per-lane (m173: pre-swizzled source pattern).
static __device__ __forceinline__ void gl_lds16(const void* g, void* l) {
    __builtin_amdgcn_global_load_lds((gv_t*)(uintptr_t)g,
                                     (lv_t*)(unsigned)(uintptr_t)l, 16, 0, 0);
}

// ---------------------------------------------------------------------------
// bf16 helpers (RNE), bit-exact with __float2bfloat16
// ---------------------------------------------------------------------------
static __device__ __forceinline__ unsigned short f2bf(float f) {
    unsigned int u = __float_as_uint(f);
    unsigned int r = (u + 0x7FFFu + ((u >> 16) & 1u)) >> 16;
    return (unsigned short)r;
}
static __device__ __forceinline__ float bf2f(unsigned short s) {
    return __uint_as_float(((unsigned int)s) << 16);
}

// ---------------------------------------------------------------------------
// Shared device helper: encoder (x -> z[64]), exact fp32.
// ---------------------------------------------------------------------------
__device__ __forceinline__ void encode_row(
    const float* __restrict__ xin,
    const float* __restrict__ W1, const float* __restrict__ b1,
    const float* __restrict__ W2, const float* __restrict__ b2,
    const float* __restrict__ W3, const float* __restrict__ b3,
    const float* __restrict__ W4, const float* __restrict__ b4,
    float* __restrict__ z) {
    float h1[16];
#pragma unroll
    for (int k = 0; k < 16; ++k) {
        float a = b1[k];
#pragma unroll
        for (int i = 0; i < 5; ++i) a = fmaf(xin[i], W1[i * 16 + k], a);
        h1[k] = fmaxf(a, 0.f);
    }
    float h2[32];
#pragma unroll
    for (int k = 0; k < 32; ++k) {
        float a = b2[k];
#pragma unroll
        for (int i = 0; i < 16; ++i) a = fmaf(h1[i], W2[i * 32 + k], a);
        h2[k] = fmaxf(a, 0.f);
    }
    float h3[16];
#pragma unroll
    for (int k = 0; k < 16; ++k) {
        float a = b3[k];
#pragma unroll
        for (int i = 0; i < 32; ++i) a = fmaf(h2[i], W3[i * 16 + k], a);
        h3[k] = fmaxf(a, 0.f);
    }
#pragma unroll
    for (int k = 0; k < ZDIM; ++k) {
        float a = b4[k];
#pragma unroll
        for (int i = 0; i < 16; ++i) a = fmaf(h3[i], W4[i * 64 + k], a);
        z[k] = a;
    }
}

// ---------------------------------------------------------------------------
// Kernel P: codebook prep only. Ebf = bf16(E), eNormHalf = 0.5*|bf16(e)|^2.
// ---------------------------------------------------------------------------
__global__ __launch_bounds__(THREADS) void prep_kernel(
    const float* __restrict__ E,
    unsigned short* __restrict__ Ebf,
    float* __restrict__ eNormHalf) {
    const int row = blockIdx.x * THREADS + threadIdx.x;
    if (row < NE) {
        float s = 0.f;
#pragma unroll
        for (int d = 0; d < ZDIM; ++d) {
            unsigned short bb = f2bf(E[row * ZDIM + d]);
            Ebf[row * ZDIM + d] = bb;
            float v = bf2f(bb);
            s = fmaf(v, v, s);
        }
        eNormHalf[row] = 0.5f * s;
    }
}

// ---------------------------------------------------------------------------
// Kernel M (mega, R15 = exact R12 revert — best measured at 72.9 us):
// 256 threads (4 waves x 64 rows), 512 blocks, z held in VGPRs (free: LDS
// caps occupancy at 2 blocks/CU, not the ~120 VGPRs). Swizzled zbuf
// (0 conflicts, R12-measured), validated DMA source-swizzle pipeline,
// 4 chunks x 512 cols, unconditional argmax (R14's wave-uniform skip was
// null-to-negative — argmax issue cost is NOT the limiter; the scan sits at
// a dependency-latency plateau at the geometry-pinned 2 waves/SIMD).
// ---------------------------------------------------------------------------
__global__ __launch_bounds__(THREADS, 2) void mega_kernel(
    const float* __restrict__ x,
    const float* __restrict__ W1, const float* __restrict__ b1,
    const float* __restrict__ W2, const float* __restrict__ b2,
    const float* __restrict__ W3, const float* __restrict__ b3,
    const float* __restrict__ W4, const float* __restrict__ b4,
    const float* __restrict__ W5, const float* __restrict__ b5,
    const float* __restrict__ W6, const float* __restrict__ b6,
    const float* __restrict__ W7, const float* __restrict__ b7,
    const float* __restrict__ W8, const float* __restrict__ b8,
    const float* __restrict__ E,
    const unsigned short* __restrict__ Ebf,
    const float* __restrict__ eNormHalf,
    float* __restrict__ partials) {

    __shared__ unsigned short ebuf[512 * ZDIM];  // 64 KB; first 32 KB = zbuf
    __shared__ float enorm[NE];                  // 8 KB
    __shared__ float sl[THREADS / 64], se[THREADS / 64];

    const int tid = threadIdx.x;
    const int lane = tid & 63;
    const int w = tid >> 6;  // 0..3
    const int l15 = lane & 15;
    const int lhi = lane >> 4;

    // ---- stage full eNormHalf -> LDS (8 KB) ----
    {
        const float4* es = (const float4*)eNormHalf;
        float4* ed = (float4*)enorm;
        ed[tid] = es[tid];
        ed[tid + 256] = es[tid + 256];
    }

    // ================= phase 1: encoder (z stays in VGPRs) =================
    const int myrow = blockIdx.x * 256 + tid;
    float xin[5];
#pragma unroll
    for (int i = 0; i < 5; ++i) xin[i] = x[myrow * 5 + i];
    float z[ZDIM];
    encode_row(xin, W1, b1, W2, b2, W3, b3, W4, b4, z);

    // bf16 z -> LDS zbuf, XOR-swizzled 16B slots: row t, slot q at
    // t*128 + ((q ^ (t&7))<<4)  -> conflict-free (R12 measured 0)
#pragma unroll
    for (int q = 0; q < 8; ++q) {
        short8 v;
#pragma unroll
        for (int e = 0; e < 8; ++e) v[e] = (short)f2bf(z[q * 8 + e]);
        *(short8*)((char*)ebuf + tid * 128 + ((q ^ (tid & 7)) << 4)) = v;
    }
    __syncthreads();

    // ---- A fragments: 4 m-tiles x 2 k-halves from swizzled zbuf ----
    // value (row, slot) at row*128 + ((slot ^ (row&7))<<4); slot = h*4+lhi,
    // row = w*64 + mt*16 + l15 -> row&7 = l15&7 (w*64, mt*16 ≡ 0 mod 8).
    short8 afr[4][2];
#pragma unroll
    for (int mt = 0; mt < 4; ++mt)
#pragma unroll
        for (int h = 0; h < 2; ++h) {
            const int row = w * 64 + mt * 16 + l15;
            const int slot = h * 4 + lhi;
            afr[mt][h] = *(const short8*)((const char*)ebuf + row * 128 +
                                          ((slot ^ (l15 & 7)) << 4));
        }
    __syncthreads();  // afr loads complete before DMA overwrites ebuf

    // ================= phase 2: scan (R9/R10-validated core) ===============
    float best[4][4];
    int bidx[4][4];
#pragma unroll
    for (int mt = 0; mt < 4; ++mt)
#pragma unroll
        for (int r = 0; r < 4; ++r) {
            best[mt][r] = -INFINITY;
            bidx[mt][r] = 0;
        }

    // per-lane pre-swizzled global byte offset (16 issues x 4 KB per chunk):
    // linear LDS slot L = q*4096 + tid*16 -> col = q*32 + (tid>>3), kb' = tid&7;
    // source slot = (col, kb' ^ (col&7)); col&7 == (tid>>3)&7 (q*32 = 0 mod 8).
    const int pi = (tid >> 3) * 128 + (((tid & 7) ^ ((tid >> 3) & 7)) << 4);
    const char* gb = (const char*)Ebf;
    const int ldsw = w * 1024;  // wave-uniform DMA dest base (lane*16 HW-added)

    // per-lane LDS read bases (validated swizzle), hoisted
    const char* base0 =
        (const char*)&ebuf[0] + l15 * 128 + ((lhi ^ (l15 & 7)) << 4);
    const char* base1 =
        (const char*)&ebuf[0] + l15 * 128 + (((4 + lhi) ^ (l15 & 7)) << 4);
    const float* enb = enorm + l15;

    for (int c = 0; c < 4; ++c) {
        // ---- stage chunk c (16 DMA issues per thread) ----
#pragma unroll
        for (int q = 0; q < 16; ++q)
            gl_lds16(gb + c * 65536 + q * 4096 + pi,
                     (char*)&ebuf[0] + q * 4096 + ldsw);
        __syncthreads();  // full drain (vmcnt+lgkm) + barrier

        const float* enc = enb + c * 512;
        const int nb = c * 512 + l15;

        // ---- 32 tiles, barrier-free (all ds_read offsets fit immediates) ----
#pragma unroll 4
        for (int t = 0; t < 32; ++t) {
            short8 b0 = *(const short8*)(base0 + t * 2048);
            short8 b1 = *(const short8*)(base1 + t * 2048);
            const float negE = -enc[t * 16];
            f32x4 ci;
            ci[0] = negE; ci[1] = negE; ci[2] = negE; ci[3] = negE;

            f32x4 acc[4];
#pragma unroll
            for (int mt = 0; mt < 4; ++mt) {
                acc[mt] = __builtin_amdgcn_mfma_f32_16x16x32_bf16(afr[mt][0], b0, ci, 0, 0, 0);
                acc[mt] = __builtin_amdgcn_mfma_f32_16x16x32_bf16(afr[mt][1], b1, acc[mt], 0, 0, 0);
            }

            const int n = nb + t * 16;
#pragma unroll
            for (int mt = 0; mt < 4; ++mt) {
#pragma unroll
                for (int r = 0; r < 4; ++r) {
                    float s = acc[mt][r];
                    if (s > best[mt][r]) {  // strict '>' keeps first index
                        best[mt][r] = s;
                        bidx[mt][r] = n;
                    }
                }
            }
        }
        __syncthreads();  // all waves done reading before next chunk's DMA
    }

    // ---- cross-lane reduction (16 lanes per row-group) -> idx into LDS ----
    int* idxbuf = (int*)ebuf;  // ebuf free after last chunk barrier
#pragma unroll
    for (int mt = 0; mt < 4; ++mt)
#pragma unroll
        for (int r = 0; r < 4; ++r) {
            float s = best[mt][r];
            int ix = bidx[mt][r];
#pragma unroll
            for (int off = 1; off < 16; off <<= 1) {
                float os = __shfl_xor(s, off);
                int oi = __shfl_xor(ix, off);
                bool take = (os > s) || (os == s && oi < ix);
                s = take ? os : s;
                ix = take ? oi : ix;
            }
            if (l15 == 0)
                idxbuf[w * 64 + mt * 16 + lhi * 4 + r] = ix;
        }
    __syncthreads();

    // ================= phase 3: gather + decoder + losses ==================
    const int myidx = idxbuf[tid];

    float zq[ZDIM];
#pragma unroll
    for (int d = 0; d < ZDIM; ++d) zq[d] = E[myidx * ZDIM + d];

    float emb = 0.f;
#pragma unroll
    for (int d = 0; d < ZDIM; ++d) {
        float diff = z[d] - zq[d];
        emb = fmaf(diff, diff, emb);
    }
    emb *= 2.0f;  // embed + BETA*commit, BETA=1

    float g1[16];
#pragma unroll
    for (int k = 0; k < 16; ++k) {
        float a = b5[k];
#pragma unroll
        for (int i = 0; i < ZDIM; ++i) a = fmaf(zq[i], W5[i * 16 + k], a);
        g1[k] = fmaxf(a, 0.f);
    }
    float g2[32];
#pragma unroll
    for (int k = 0; k < 32; ++k) {
        float a = b6[k];
#pragma unroll
        for (int i = 0; i < 16; ++i) a = fmaf(g1[i], W6[i * 32 + k], a);
        g2[k] = fmaxf(a, 0.f);
    }
    float g3[16];
#pragma unroll
    for (int k = 0; k < 16; ++k) {
        float a = b7[k];
#pragma unroll
        for (int i = 0; i < 32; ++i) a = fmaf(g2[i], W7[i * 16 + k], a);
        g3[k] = fmaxf(a, 0.f);
    }
    float l2 = 0.f;
#pragma unroll
    for (int k = 0; k < 5; ++k) {
        float a = b8[k];
#pragma unroll
        for (int i = 0; i < 16; ++i) a = fmaf(g3[i], W8[i * 5 + k], a);
        float diff = xin[k] - a;
        l2 = fmaf(diff, diff, l2);
    }

#pragma unroll
    for (int off = 32; off > 0; off >>= 1) {
        l2 += __shfl_down(l2, off);
        emb += __shfl_down(emb, off);
    }
    if ((tid & 63) == 0) {
        sl[w] = l2;
        se[w] = emb;
    }
    __syncthreads();
    if (tid == 0) {
        float L = 0.f, Em = 0.f;
#pragma unroll
        for (int ww = 0; ww < THREADS / 64; ++ww) {
            L += sl[ww];
            Em += se[ww];
        }
        partials[2 * blockIdx.x + 0] = L;
        partials[2 * blockIdx.x + 1] = Em;
    }
}

// ---------------------------------------------------------------------------
// Fallback path kernels (ws too small) — proven R1 monolithic fp32.
// ---------------------------------------------------------------------------
__global__ void enorm_kernel(const float* __restrict__ E,
                             float* __restrict__ eNormHalf) {
    int j = blockIdx.x * blockDim.x + threadIdx.x;
    if (j < NE) {
        float s = 0.f;
#pragma unroll
        for (int d = 0; d < ZDIM; ++d) {
            float v = E[j * ZDIM + d];
            s = fmaf(v, v, s);
        }
        eNormHalf[j] = 0.5f * s;
    }
}

__global__ __launch_bounds__(THREADS) void vqvae_main_kernel(
    const float* __restrict__ x,
    const float* __restrict__ W1, const float* __restrict__ b1,
    const float* __restrict__ W2, const float* __restrict__ b2,
    const float* __restrict__ W3, const float* __restrict__ b3,
    const float* __restrict__ W4, const float* __restrict__ b4,
    const float* __restrict__ W5, const float* __restrict__ b5,
    const float* __restrict__ W6, const float* __restrict__ b6,
    const float* __restrict__ W7, const float* __restrict__ b7,
    const float* __restrict__ W8, const float* __restrict__ b8,
    const float* __restrict__ E, const float* __restrict__ eNormHalf,
    float* __restrict__ partials) {

    const int row = blockIdx.x * blockDim.x + threadIdx.x;
    float l2 = 0.f, emb = 0.f;

    if (row < B_ROWS) {
        float xin[5];
#pragma unroll
        for (int i = 0; i < 5; ++i) xin[i] = x[row * 5 + i];
        float z[ZDIM];
        encode_row(xin, W1, b1, W2, b2, W3, b3, W4, b4, z);

        float best = -INFINITY;
        int bidx = 0;
        const float4* __restrict__ E4 = reinterpret_cast<const float4*>(E);
        for (int j = 0; j < NE; ++j) {
            float a0 = 0.f, a1 = 0.f, a2 = 0.f, a3 = 0.f;
#pragma unroll
            for (int q = 0; q < ZDIM / 4; ++q) {
                float4 e = E4[j * (ZDIM / 4) + q];
                a0 = fmaf(z[4 * q + 0], e.x, a0);
                a1 = fmaf(z[4 * q + 1], e.y, a1);
                a2 = fmaf(z[4 * q + 2], e.z, a2);
                a3 = fmaf(z[4 * q + 3], e.w, a3);
            }
            float score = ((a0 + a1) + (a2 + a3)) - eNormHalf[j];
            if (score > best) { best = score; bidx = j; }
        }
        float zq[ZDIM];
#pragma unroll
        for (int d = 0; d < ZDIM; ++d) zq[d] = E[bidx * ZDIM + d];
#pragma unroll
        for (int d = 0; d < ZDIM; ++d) {
            float diff = z[d] - zq[d];
            emb = fmaf(diff, diff, emb);
        }
        emb *= 2.0f;
        float g1[16];
#pragma unroll
        for (int k = 0; k < 16; ++k) {
            float a = b5[k];
#pragma unroll
            for (int i = 0; i < ZDIM; ++i) a = fmaf(zq[i], W5[i * 16 + k], a);
            g1[k] = fmaxf(a, 0.f);
        }
        float g2[32];
#pragma unroll
        for (int k = 0; k < 32; ++k) {
            float a = b6[k];
#pragma unroll
            for (int i = 0; i < 16; ++i) a = fmaf(g1[i], W6[i * 32 + k], a);
            g2[k] = fmaxf(a, 0.f);
        }
        float g3[16];
#pragma unroll
        for (int k = 0; k < 16; ++k) {
            float a = b7[k];
#pragma unroll
            for (int i = 0; i < 32; ++i) a = fmaf(g2[i], W7[i * 16 + k], a);
            g3[k] = fmaxf(a, 0.f);
        }
#pragma unroll
        for (int k = 0; k < 5; ++k) {
            float a = b8[k];
#pragma unroll
            for (int i = 0; i < 16; ++i) a = fmaf(g3[i], W8[i * 5 + k], a);
            float diff = xin[k] - a;
            l2 = fmaf(diff, diff, l2);
        }
    }
#pragma unroll
    for (int off = 32; off > 0; off >>= 1) {
        l2 += __shfl_down(l2, off);
        emb += __shfl_down(emb, off);
    }
    __shared__ float sl[THREADS / 64], se[THREADS / 64];
    const int wid = threadIdx.x >> 6;
    if ((threadIdx.x & 63) == 0) { sl[wid] = l2; se[wid] = emb; }
    __syncthreads();
    if (threadIdx.x == 0) {
        float L = 0.f, Em = 0.f;
#pragma unroll
        for (int ww = 0; ww < THREADS / 64; ++ww) { L += sl[ww]; Em += se[ww]; }
        partials[2 * blockIdx.x + 0] = L;
        partials[2 * blockIdx.x + 1] = Em;
    }
}

// ---------------------------------------------------------------------------
// Final reduce: per-block partials (double accumulation) -> 3 scalars.
// ---------------------------------------------------------------------------
__global__ void finalize_kernel(const float* __restrict__ partials, int nblocks,
                                float* __restrict__ out) {
    __shared__ double sl[256], se[256];
    double a = 0.0, b = 0.0;
    for (int i = threadIdx.x; i < nblocks; i += 256) {
        a += (double)partials[2 * i + 0];
        b += (double)partials[2 * i + 1];
    }
    sl[threadIdx.x] = a;
    se[threadIdx.x] = b;
    __syncthreads();
    for (int s = 128; s > 0; s >>= 1) {
        if (threadIdx.x < s) {
            sl[threadIdx.x] += sl[threadIdx.x + s];
            se[threadIdx.x] += se[threadIdx.x + s];
        }
        __syncthreads();
    }
    if (threadIdx.x == 0) {
        double sum_l2 = sl[0];
        double embd = se[0];
        double c = -0.5 * 5.0 * log(2.0 * M_PI / 10.0);
        double neg_pxz = -(c - 5.0 * sum_l2);
        out[0] = (float)(neg_pxz + embd);
        out[1] = (float)neg_pxz;
        out[2] = (float)embd;
    }
}

// ---------------------------------------------------------------------------
extern "C" void kernel_launch(void* const* d_in, const int* in_sizes, int n_in,
                              void* d_out, int out_size, void* d_ws,
                              size_t ws_size, hipStream_t stream) {
    const float* x = (const float*)d_in[0];
    const float* W1 = (const float*)d_in[1];
    const float* b1 = (const float*)d_in[2];
    const float* W2 = (const float*)d_in[3];
    const float* b2 = (const float*)d_in[4];
    const float* W3 = (const float*)d_in[5];
    const float* b3 = (const float*)d_in[6];
    const float* W4 = (const float*)d_in[7];
    const float* b4 = (const float*)d_in[8];
    const float* W5 = (const float*)d_in[9];
    const float* b5 = (const float*)d_in[10];
    const float* W6 = (const float*)d_in[11];
    const float* b6 = (const float*)d_in[12];
    const float* W7 = (const float*)d_in[13];
    const float* b7 = (const float*)d_in[14];
    const float* W8 = (const float*)d_in[15];
    const float* b8 = (const float*)d_in[16];
    const float* E = (const float*)d_in[17];

    // ws layout (16B-aligned segments)
    char* ws = (char*)d_ws;
    unsigned short* Ebf      = (unsigned short*)(ws + 0);       // 256 KB
    float*          eNormH   = (float*)(ws + 262144);           // 8 KB
    float*          partials = (float*)(ws + 270336);           // 4 KB
    const size_t need = 270336 + 512 * 2 * sizeof(float);

    if (ws_size >= need) {
        const int mblocks = B_ROWS / 256;  // 512
        prep_kernel<<<NE / THREADS, THREADS, 0, stream>>>(E, Ebf, eNormH);
        mega_kernel<<<mblocks, THREADS, 0, stream>>>(
            x, W1, b1, W2, b2, W3, b3, W4, b4, W5, b5, W6, b6, W7, b7, W8, b8,
            E, Ebf, eNormH, partials);
        finalize_kernel<<<1, 256, 0, stream>>>(partials, mblocks, (float*)d_out);
    } else {
        // fallback: proven fp32 monolithic path
        const int nblocks = B_ROWS / THREADS;  // 512
        float* eNormFB = (float*)ws;           // 8 KB
        float* partFB  = (float*)(ws + 16384);
        enorm_kernel<<<(NE + THREADS - 1) / THREADS, THREADS, 0, stream>>>(E, eNormFB);
        vqvae_main_kernel<<<nblocks, THREADS, 0, stream>>>(
            x, W1, b1, W2, b2, W3, b3, W4, b4, W5, b5, W6, b6, W7, b7, W8, b8,
            E, eNormFB, partFB);
        finalize_kernel<<<1, 256, 0, stream>>>(partFB, nblocks, (float*)d_out);
    }
}